// Round 9
// baseline (141.515 us; speedup 1.0000x reference)
//
#include <hip/hip_runtime.h>
#include <hip/hip_fp16.h>

// ---------------- problem constants ----------------
#define BATCH 64
#define HH    28
#define WW2   28
#define HWPX  784          // 28*28
#define PTOT  50176        // 64*784
#define CIN   384
#define DIM   96
#define MDIM  64
#define JTOT  82944        // DIM*DIM*9
#define WSAMP 82944        // per-sample conv weights (96*864)

// ws layout (bytes)
#define XD_OFF 0u                       // P*96 f16 = 9,633,792
#define Y_OFF  9633792u                 // P*96 f16
#define WP_OFF 19267584u                // 64*82944 f16 = 10,616,832
#define HS_OFF 29884416u                // 64*64 f32
#define Z_OFF  29900800u                // 64*64 f32
#define WUT_OFF 29917184u               // 384*96 f16 = 73,728
// Wt (f16 [160][384] = 122,880 B) lives at WP_OFF: consumed by k1 BEFORE
// k2b overwrites the wperm region. Single stream -> deterministic.

typedef _Float16 f16x8 __attribute__((ext_vector_type(8)));
typedef _Float16 f16x4 __attribute__((ext_vector_type(4)));
typedef float f32x4 __attribute__((ext_vector_type(4)));

__device__ __forceinline__ float qgelu(float v) {
    return v / (1.f + __expf(-1.702f * v));
}

// ============================================================
// K0: convert [Wm1 | Wd] -> Wt f16 [o=160][k=384]
//     and Wu [96][384] -> WuT f16 [c=384][d=96]
// ============================================================
__global__ void k0_wcvt(const float* __restrict__ Wm1,
                        const float* __restrict__ Wd,
                        const float* __restrict__ Wu,
                        _Float16* __restrict__ Wt,
                        _Float16* __restrict__ WuT)
{
    int i = blockIdx.x * 256 + threadIdx.x;   // < 98304
    if (i < 61440) {
        int o = i / CIN, k = i - o * CIN;
        float v = (o < MDIM) ? Wm1[k * MDIM + o] : Wd[k * DIM + (o - MDIM)];
        Wt[i] = (_Float16)v;
    } else {
        int j = i - 61440;                    // < 36864
        int c = j / DIM, d = j - c * DIM;
        WuT[j] = (_Float16)Wu[d * CIN + c];
    }
}

// ============================================================
// K1: MFMA GEMM  C[P,160] = f16(x)[P,384] @ Wt^T, fused epilogues:
//   cols 0..63  : relu(+bm1) -> per-sample sum -> hsum (atomics)
//   cols 64..159: quick_gelu(+bd) -> xd f16
// grid 392, block 512 (8 waves: 4m x 2n). Tile M=128, N=160, KC=32.
// r3's measured-best variant (58 us): single-buffer LDS, 1-deep register
// prefetch, 2 barriers/iter. Six structural variants (dbuf, 2/3-deep,
// M=64, N-split, direct-global) all landed 66-133 us — this is the
// lockstep structure's local optimum. Do not re-roll.
// ============================================================
__global__ __launch_bounds__(512, 4) void k1_mfma(
    const float* __restrict__ x, const _Float16* __restrict__ Wt,
    const float* __restrict__ bm1, const float* __restrict__ bd,
    float* __restrict__ hsum, __half* __restrict__ xd)
{
    __shared__ char smem[25088];
    _Float16* As  = (_Float16*)smem;            // [128][40] f16
    _Float16* Bs  = (_Float16*)(smem + 10240);  // [160][40] f16
    _Float16* xds = (_Float16*)smem;            // [128][96] f16 (epilogue)
    float*   hred = (float*)(smem + 24576);     // [2][64] f32

    const int t = threadIdx.x;
    const int p0 = blockIdx.x * 128;
    const int lane = t & 63, w = t >> 6;
    const int wm = w >> 1, wn = w & 1;          // 4 x 2 wave grid

    f32x4 acc[2][5];
    #pragma unroll
    for (int mf = 0; mf < 2; ++mf)
        #pragma unroll
        for (int nf = 0; nf < 5; ++nf) acc[mf][nf] = (f32x4){0.f, 0.f, 0.f, 0.f};

    float4 ra[2];
    uint4  rb0, rb1;
    const int ar0 = t >> 3, aq0 = t & 7;
    const int ar1 = (t + 512) >> 3, aq1 = t & 7;
    const int br0 = t >> 2, bq0 = t & 3;
    const int br1 = (t + 512) >> 2, bq1 = t & 3;

    {
        const int k0 = 0;
        ra[0] = *(const float4*)(x + (size_t)(p0 + ar0) * CIN + k0 + aq0 * 4);
        ra[1] = *(const float4*)(x + (size_t)(p0 + ar1) * CIN + k0 + aq1 * 4);
        rb0 = *(const uint4*)(Wt + br0 * CIN + k0 + bq0 * 8);
        if (t < 128) rb1 = *(const uint4*)(Wt + br1 * CIN + k0 + bq1 * 8);
    }

    for (int kc = 0; kc < 12; ++kc) {
        #pragma unroll
        for (int i = 0; i < 2; ++i) {
            const int r = i ? ar1 : ar0, q = i ? aq1 : aq0;
            f16x4 h;
            h[0] = (_Float16)ra[i].x; h[1] = (_Float16)ra[i].y;
            h[2] = (_Float16)ra[i].z; h[3] = (_Float16)ra[i].w;
            *(f16x4*)(As + r * 40 + q * 4) = h;
        }
        *(uint4*)(Bs + br0 * 40 + bq0 * 8) = rb0;
        if (t < 128) *(uint4*)(Bs + br1 * 40 + bq1 * 8) = rb1;
        __syncthreads();

        if (kc + 1 < 12) {
            const int k0 = (kc + 1) * 32;
            ra[0] = *(const float4*)(x + (size_t)(p0 + ar0) * CIN + k0 + aq0 * 4);
            ra[1] = *(const float4*)(x + (size_t)(p0 + ar1) * CIN + k0 + aq1 * 4);
            rb0 = *(const uint4*)(Wt + br0 * CIN + k0 + bq0 * 8);
            if (t < 128) rb1 = *(const uint4*)(Wt + br1 * CIN + k0 + bq1 * 8);
        }

        const int ko = (lane >> 4) * 8;
        const int rl = lane & 15;
        f16x8 av[2], bv[5];
        av[0] = *(f16x8*)(As + (wm * 32 + rl) * 40 + ko);
        av[1] = *(f16x8*)(As + (wm * 32 + 16 + rl) * 40 + ko);
        #pragma unroll
        for (int nf = 0; nf < 5; ++nf)
            bv[nf] = *(f16x8*)(Bs + (wn * 80 + nf * 16 + rl) * 40 + ko);
        #pragma unroll
        for (int mf = 0; mf < 2; ++mf)
            #pragma unroll
            for (int nf = 0; nf < 5; ++nf)
                acc[mf][nf] = __builtin_amdgcn_mfma_f32_16x16x32_f16(
                    av[mf], bv[nf], acc[mf][nf], 0, 0, 0);
        __syncthreads();
    }

    if (t < 128) hred[t] = 0.f;
    __syncthreads();

    const int s0 = p0 / HWPX, s_last = (p0 + 127) / HWPX;
    #pragma unroll
    for (int mf = 0; mf < 2; ++mf) {
        #pragma unroll
        for (int nf = 0; nf < 5; ++nf) {
            const int col = wn * 80 + nf * 16 + (lane & 15);
            #pragma unroll
            for (int j = 0; j < 4; ++j) {
                const int rl = wm * 32 + mf * 16 + (lane >> 4) * 4 + j;
                float v = acc[mf][nf][j];
                if (col < 64) {
                    v = fmaxf(v + bm1[col], 0.f);
                    int sloc = (p0 + rl) / HWPX - s0;
                    atomicAdd(&hred[sloc * 64 + col], v);
                } else {
                    int e = col - 64;
                    xds[rl * 96 + e] = (_Float16)qgelu(v + bd[e]);
                }
            }
        }
    }
    __syncthreads();

    if (t < 128) {
        int sloc = t >> 6, col = t & 63, s = s0 + sloc;
        if (s <= s_last) atomicAdd(&hsum[s * 64 + col], hred[t]);
    }
    #pragma unroll
    for (int i = 0; i < 3; ++i) {
        int e = t + i * 512;
        *(uint4*)((__half*)xd + (size_t)p0 * 96 + e * 8) = *(uint4*)(xds + e * 8);
    }
}

// ============================================================
// K2a: z[b][m] = emb[m] + (hsum[b]/784)@Wm2 + bm2[m]
// ============================================================
__global__ void k2a_prompt(const float* __restrict__ hsum,
                           const float* __restrict__ Wm2,
                           const float* __restrict__ bm2,
                           const float* __restrict__ emb,
                           float* __restrict__ z)
{
    int idx = blockIdx.x * 256 + threadIdx.x;   // 4096
    int b = idx >> 6, m = idx & 63;
    float acc = 0.f;
    #pragma unroll 8
    for (int d = 0; d < 64; ++d) acc += hsum[b * 64 + d] * Wm2[d * 64 + m];
    z[idx] = emb[m] + acc * (1.f / 784.f) + bm2[m];
}

// ============================================================
// K2b: wflat[b][j] = z[b]@Wh[:,j] + bh[j], stored PERMUTED as
//      wperm[b][o][t9*96+i] (f16).
// v2: coalesced-store rewrite. grid 384 = 96 o-groups x 4 quarters.
// Block handles j = o*864 + qd*216 + t (216 consecutive Wh columns,
// coalesced reads, each Wh element read once), computes all 64 samples,
// repacks through LDS into destination order, stores uint2 (4 f16) in
// 48-B contiguous runs. Old version: 2-B scattered stores at stride
// 192 B (~24-32x write amplification).
// ============================================================
__global__ __launch_bounds__(256) void k2b_hyper(
    const float* __restrict__ z, const float* __restrict__ Wh,
    const float* __restrict__ bh, __half* __restrict__ wperm)
{
    __shared__ float  zs[4096];          // 16 KB
    __shared__ __half wl[64 * 216];      // 27648 B
    const int t = threadIdx.x;
    const int o = blockIdx.x >> 2, qd = blockIdx.x & 3;

    for (int idx = t; idx < 4096; idx += 256) zs[idx] = z[idx];

    const bool act = (t < 216);
    const int j = o * 864 + qd * 216 + (act ? t : 0);
    float wh[64];
    float bj = 0.f;
    if (act) {
        #pragma unroll 8
        for (int m = 0; m < 64; ++m) wh[m] = Wh[(size_t)m * JTOT + j];
        bj = bh[j];
    }
    __syncthreads();

    if (act) {
        const int il = t / 9, t9 = t - il * 9;   // i_local in [0,24), tap
        const int loc = t9 * 24 + il;            // destination-ordered slot
        for (int b = 0; b < 64; ++b) {
            float a = bj;
            const float4* zz = (const float4*)(zs + b * 64);
            #pragma unroll
            for (int m4 = 0; m4 < 16; ++m4) {
                float4 v = zz[m4];
                a += v.x * wh[4 * m4] + v.y * wh[4 * m4 + 1] +
                     v.z * wh[4 * m4 + 2] + v.w * wh[4 * m4 + 3];
            }
            wl[b * 216 + loc] = __float2half(a);
        }
    }
    __syncthreads();

    // stores: 64 b x 9 t9 x 6 uint2 = 3456 uint2 (8 B each, 48-B runs)
    for (int idx = t; idx < 3456; idx += 256) {
        int b = idx / 54, r = idx - b * 54;
        int t9 = r / 6, il4 = r - t9 * 6;
        *(uint2*)(wperm + (size_t)b * WSAMP + o * 864 + t9 * 96 + qd * 24 + il4 * 4) =
            *(const uint2*)(wl + b * 216 + t9 * 24 + il4 * 4);
    }
}

// ============================================================
// K3: MFMA implicit-GEMM grouped 3x3 conv + quick_gelu.
// grid 448 (XCD-grouped swizzle), block 256 (4 waves, 2m x 2n).
// ============================================================
__global__ __launch_bounds__(256) void k3_mfma(
    const __half* __restrict__ xd, const __half* __restrict__ wperm,
    __half* __restrict__ y)
{
    __shared__ __half sm[17600];                 // 35,200 B
    const int t = threadIdx.x;

    const int n = blockIdx.x;                    // 448
    const int xcd = n & 7, jj0 = n >> 3;         // jj0 < 56
    const int b = xcd * 8 + jj0 / 7;
    const int rt = jj0 % 7;
    const int h0 = rt * 4;

    if (t < 16) *(uint4*)(sm + 17472 + t * 8) = uint4{0u, 0u, 0u, 0u};
    for (int idx = t; idx < 2016; idx += 256) {
        int pix = idx / 12, q = idx - pix * 12;
        int r = pix / 28, col = pix - r * 28;
        int g = h0 - 1 + r;
        uint4 v = {0u, 0u, 0u, 0u};
        if ((unsigned)g < 28u)
            v = *(const uint4*)(xd + (size_t)(b * HWPX + g * 28 + col) * 96 + q * 8);
        *(uint4*)(sm + pix * 104 + q * 8) = v;
    }
    __syncthreads();

    const int lane = t & 63, w = t >> 6;
    const int wm = w >> 1, wn = w & 1;
    const int mloc = lane & 15, klo = (lane >> 4) * 8;
    const int base_m = wm * 64;

    int oh_[4], ow_[4]; bool pv[4];
    #pragma unroll
    for (int mf = 0; mf < 4; ++mf) {
        int p = base_m + mf * 16 + mloc;
        pv[mf] = (p < 112);
        int pp = pv[mf] ? p : 0;
        oh_[mf] = pp / 28; ow_[mf] = pp - oh_[mf] * 28;
    }
    const __half* wp = wperm + (size_t)b * WSAMP + (wn * 48 + mloc) * 864 + klo;

    f32x4 acc[4][3];
    #pragma unroll
    for (int mf = 0; mf < 4; ++mf)
        #pragma unroll
        for (int nf = 0; nf < 3; ++nf) acc[mf][nf] = (f32x4){0.f, 0.f, 0.f, 0.f};

    #pragma unroll
    for (int kh = 0; kh < 3; ++kh) {
        #pragma unroll
        for (int kw = 0; kw < 3; ++kw) {
            const int t9 = kh * 3 + kw;
            int abase[4];
            #pragma unroll
            for (int mf = 0; mf < 4; ++mf) {
                int iw = ow_[mf] + kw - 1;
                bool valid = pv[mf] && ((unsigned)iw < 28u);
                abase[mf] = valid ? ((oh_[mf] + kh) * 28 + iw) * 104 + klo
                                  : 17472 + klo;
            }
            #pragma unroll
            for (int ic = 0; ic < 3; ++ic) {
                f16x8 av[4], bv[3];
                #pragma unroll
                for (int nf = 0; nf < 3; ++nf)
                    bv[nf] = *(const f16x8*)(wp + nf * 13824 + t9 * 96 + ic * 32);
                #pragma unroll
                for (int mf = 0; mf < 4; ++mf)
                    av[mf] = *(const f16x8*)(sm + abase[mf] + ic * 32);
                #pragma unroll
                for (int mf = 0; mf < 4; ++mf)
                    #pragma unroll
                    for (int nf = 0; nf < 3; ++nf)
                        acc[mf][nf] = __builtin_amdgcn_mfma_f32_16x16x32_f16(
                            av[mf], bv[nf], acc[mf][nf], 0, 0, 0);
            }
        }
    }
    __syncthreads();

    #pragma unroll
    for (int mf = 0; mf < 4; ++mf) {
        #pragma unroll
        for (int nf = 0; nf < 3; ++nf) {
            const int o = wn * 48 + nf * 16 + mloc;
            #pragma unroll
            for (int j = 0; j < 4; ++j) {
                int p = base_m + mf * 16 + (lane >> 4) * 4 + j;
                if (p < 112)
                    sm[p * 104 + o] = __float2half(qgelu(acc[mf][nf][j]));
            }
        }
    }
    __syncthreads();
    for (int idx = t; idx < 1344; idx += 256) {
        int pix = idx / 12, q = idx - pix * 12;
        *(uint4*)(y + (size_t)(b * HWPX + h0 * 28 + pix) * 96 + q * 8) =
            *(uint4*)(sm + pix * 104 + q * 8);
    }
}

// ============================================================
// K4: MFMA GEMM  out[P,384] = y[P,96] @ Wu + bu (f32 out).
// grid 392, block 512 (8 waves 2m x 4n). Tile M=128, N=384, K=96.
// ============================================================
__global__ __launch_bounds__(512, 2) void k4_mfma(
    const __half* __restrict__ y, const _Float16* __restrict__ WuT,
    const float* __restrict__ bu, float* __restrict__ out)
{
    __shared__ __half ys[128 * 104];             // 26,624 B
    const int t = threadIdx.x;
    const int p0 = blockIdx.x * 128;

    #pragma unroll
    for (int i = 0; i < 3; ++i) {
        int idx = t + i * 512;                   // < 1536
        int pix = idx / 12, q = idx - pix * 12;
        *(uint4*)(ys + pix * 104 + q * 8) =
            *(const uint4*)(y + (size_t)(p0 + pix) * 96 + q * 8);
    }

    const int lane = t & 63, w = t >> 6;
    const int wm = w >> 2, wn = w & 3;           // 2m x 4n
    const int mloc = lane & 15, klo = (lane >> 4) * 8;

    float bcol[6];
    #pragma unroll
    for (int nf = 0; nf < 6; ++nf) bcol[nf] = bu[wn * 96 + nf * 16 + mloc];
    __syncthreads();

    f32x4 acc[4][6];
    #pragma unroll
    for (int mf = 0; mf < 4; ++mf)
        #pragma unroll
        for (int nf = 0; nf < 6; ++nf) acc[mf][nf] = (f32x4){0.f, 0.f, 0.f, 0.f};

    #pragma unroll
    for (int kc = 0; kc < 3; ++kc) {
        f16x8 av[4], bv[6];
        #pragma unroll
        for (int nf = 0; nf < 6; ++nf)
            bv[nf] = *(const f16x8*)(WuT + (wn * 96 + nf * 16 + mloc) * 96 + kc * 32 + klo);
        #pragma unroll
        for (int mf = 0; mf < 4; ++mf)
            av[mf] = *(const f16x8*)(ys + (wm * 64 + mf * 16 + mloc) * 104 + kc * 32 + klo);
        #pragma unroll
        for (int mf = 0; mf < 4; ++mf)
            #pragma unroll
            for (int nf = 0; nf < 6; ++nf)
                acc[mf][nf] = __builtin_amdgcn_mfma_f32_16x16x32_f16(
                    av[mf], bv[nf], acc[mf][nf], 0, 0, 0);
    }

    #pragma unroll
    for (int mf = 0; mf < 4; ++mf) {
        #pragma unroll
        for (int nf = 0; nf < 6; ++nf) {
            const int c = wn * 96 + nf * 16 + mloc;
            #pragma unroll
            for (int j = 0; j < 4; ++j) {
                int p = p0 + wm * 64 + mf * 16 + (lane >> 4) * 4 + j;
                out[(size_t)p * CIN + c] = acc[mf][nf][j] + bcol[nf];
            }
        }
    }
}

// ============================================================
extern "C" void kernel_launch(void* const* d_in, const int* in_sizes, int n_in,
                              void* d_out, int out_size, void* d_ws, size_t ws_size,
                              hipStream_t stream)
{
    const float* x   = (const float*)d_in[0];
    const float* Wd  = (const float*)d_in[1];
    const float* bd  = (const float*)d_in[2];
    const float* Wm1 = (const float*)d_in[3];
    const float* bm1 = (const float*)d_in[4];
    const float* Wm2 = (const float*)d_in[5];
    const float* bm2 = (const float*)d_in[6];
    const float* Wh  = (const float*)d_in[7];
    const float* bh  = (const float*)d_in[8];
    const float* emb = (const float*)d_in[9];
    const float* Wu  = (const float*)d_in[10];
    const float* bu  = (const float*)d_in[11];
    float* out = (float*)d_out;

    char* ws = (char*)d_ws;
    __half*   xd    = (__half*)(ws + XD_OFF);
    __half*   ybuf  = (__half*)(ws + Y_OFF);
    __half*   wperm = (__half*)(ws + WP_OFF);
    float*    hsum  = (float*)(ws + HS_OFF);
    float*    z     = (float*)(ws + Z_OFF);
    _Float16* Wt    = (_Float16*)(ws + WP_OFF);   // transient, consumed before k2b
    _Float16* WuT   = (_Float16*)(ws + WUT_OFF);

    hipMemsetAsync(hsum, 0, 64 * 64 * sizeof(float), stream);

    k0_wcvt<<<384, 256, 0, stream>>>(Wm1, Wd, Wu, Wt, WuT);
    k1_mfma<<<392, 512, 0, stream>>>(x, Wt, bm1, bd, hsum, xd);
    k2a_prompt<<<16, 256, 0, stream>>>(hsum, Wm2, bm2, emb, z);
    k2b_hyper<<<384, 256, 0, stream>>>(z, Wh, bh, wperm);
    k3_mfma<<<448, 256, 0, stream>>>(xd, wperm, ybuf);
    k4_mfma<<<392, 512, 0, stream>>>(ybuf, WuT, bu, out);
}